// Round 17
// baseline (765.194 us; speedup 1.0000x reference)
//
#include <hip/hip_runtime.h>
#include <hip/hip_bf16.h>
#include <stdint.h>

#define N0 40000
#define N1 10000
#define N2 2500
#define N3 625
#define E0 240000
#define CIN 64
#define CH 256
#define NBLK ((N0 + 255) / 256)   // 157 scan blocks

// ---------------- degree / CSR build ----------------
__global__ void count_deg(const int* __restrict__ dst, int* __restrict__ deg, int e) {
    int i = blockIdx.x * blockDim.x + threadIdx.x;
    if (i < e) atomicAdd(&deg[dst[i]], 1);
}

__global__ __launch_bounds__(256) void scan_blocks(const int* __restrict__ deg,
                                                   int* __restrict__ incl,
                                                   int* __restrict__ bsum, int n) {
    __shared__ int s[256];
    int i = blockIdx.x * 256 + threadIdx.x;
    s[threadIdx.x] = (i < n) ? deg[i] : 0;
    __syncthreads();
#pragma unroll
    for (int off = 1; off < 256; off <<= 1) {
        int t = (threadIdx.x >= off) ? s[threadIdx.x - off] : 0;
        __syncthreads();
        s[threadIdx.x] += t;
        __syncthreads();
    }
    if (i < n) incl[i] = s[threadIdx.x];
    if (threadIdx.x == 255) bsum[blockIdx.x] = s[255];
}

__global__ __launch_bounds__(256) void scan_bsums(int* __restrict__ bsum, int nb) {
    __shared__ int s[256];
    s[threadIdx.x] = (threadIdx.x < nb) ? bsum[threadIdx.x] : 0;
    __syncthreads();
#pragma unroll
    for (int off = 1; off < 256; off <<= 1) {
        int t = (threadIdx.x >= off) ? s[threadIdx.x - off] : 0;
        __syncthreads();
        s[threadIdx.x] += t;
        __syncthreads();
    }
    if (threadIdx.x < nb) bsum[threadIdx.x] = s[threadIdx.x];
}

__global__ void finalize_rowptr(const int* __restrict__ incl, const int* __restrict__ bsum,
                                int* __restrict__ rowptr, int n) {
    int i = blockIdx.x * blockDim.x + threadIdx.x;
    if (i == 0) rowptr[0] = 0;
    if (i < n) {
        int b = i >> 8;
        int off = b ? bsum[b - 1] : 0;
        rowptr[i + 1] = incl[i] + off;
    }
}

__global__ void copy_int(const int* __restrict__ a, int* __restrict__ b, int n) {
    int i = blockIdx.x * blockDim.x + threadIdx.x;
    if (i < n) b[i] = a[i];
}
__global__ void fill_csr(const int* __restrict__ src, const int* __restrict__ dst,
                         int* __restrict__ cursor, int* __restrict__ colsrc, int e) {
    int i = blockIdx.x * blockDim.x + threadIdx.x;
    if (i < e) {
        int d = dst[i];
        int p = atomicAdd(&cursor[d], 1);
        colsrc[p] = src[i];
    }
}
__global__ void make_inv(const int* __restrict__ deg, double* __restrict__ inv, int n) {
    int i = blockIdx.x * blockDim.x + threadIdx.x;
    if (i < n) inv[i] = 1.0 / sqrt((double)(deg[i] + 1));  // +1 self loop
}

// ---------------- f32 GEMM: block = 64 rows x 256 cols (full output width, A staged once) ----------------
// out[M x 256] = A[gidx[M] x K] @ W[K x 256] (+bias). Per-output k-accumulation order unchanged.
__global__ __launch_bounds__(256) void gemm_f32(
    const float* __restrict__ A, const int* __restrict__ gidx,
    const float* __restrict__ W, const float* __restrict__ bias,
    float* __restrict__ out, int M, int K)
{
    __shared__ float As[16][68];    // [k][row]
    __shared__ float Bs[16][260];   // [k][col 0..255]; 1040B rows stay 16B-aligned, stride%32=4
    const int tid = threadIdx.x;
    const int tx = tid & 15, ty = tid >> 4;
    const int row0 = blockIdx.x * 64;
    const int sr = tid >> 2;            // 0..63 (row for A staging)
    const int skq = (tid & 3) * 4;      // k-quad for A staging
    const int bkk = tid >> 4;           // 0..15 (k-row for B staging)
    const int bc4 = (tid & 15) * 4;     // col-quad base for B staging
    const int arow = row0 + sr;
    const bool rowok = arow < M;
    long arr = 0;
    if (rowok) arr = (long)(gidx ? gidx[arow] : arow) * K;

    float acc[4][16] = {};  // [row i][col = q*4+j]
    for (int k0 = 0; k0 < K; k0 += 16) {
        float4 av = make_float4(0.f, 0.f, 0.f, 0.f);
        if (rowok) av = *reinterpret_cast<const float4*>(&A[arr + k0 + skq]);
        As[skq + 0][sr] = av.x;
        As[skq + 1][sr] = av.y;
        As[skq + 2][sr] = av.z;
        As[skq + 3][sr] = av.w;
#pragma unroll
        for (int q = 0; q < 4; ++q) {
            float4 bv = *reinterpret_cast<const float4*>(&W[(long)(k0 + bkk) * CH + q * 64 + bc4]);
            *reinterpret_cast<float4*>(&Bs[bkk][q * 64 + bc4]) = bv;
        }
        __syncthreads();
#pragma unroll
        for (int kk = 0; kk < 16; ++kk) {
            float4 a4 = *reinterpret_cast<const float4*>(&As[kk][ty * 4]);
            float a[4] = {a4.x, a4.y, a4.z, a4.w};
            float b[16];
#pragma unroll
            for (int q = 0; q < 4; ++q) {
                float4 b4 = *reinterpret_cast<const float4*>(&Bs[kk][q * 64 + tx * 4]);
                b[q * 4 + 0] = b4.x; b[q * 4 + 1] = b4.y;
                b[q * 4 + 2] = b4.z; b[q * 4 + 3] = b4.w;
            }
#pragma unroll
            for (int i = 0; i < 4; i++)
#pragma unroll
                for (int j = 0; j < 16; j++) acc[i][j] += a[i] * b[j];
        }
        __syncthreads();
    }
#pragma unroll
    for (int i = 0; i < 4; i++) {
        int row = row0 + ty * 4 + i;
        if (row >= M) continue;
#pragma unroll
        for (int q = 0; q < 4; ++q) {
            int col = q * 64 + tx * 4;
            float4 v = make_float4(acc[i][q * 4 + 0], acc[i][q * 4 + 1],
                                   acc[i][q * 4 + 2], acc[i][q * 4 + 3]);
            if (bias) {
                float4 bv = *reinterpret_cast<const float4*>(&bias[col]);
                v.x += bv.x; v.y += bv.y; v.z += bv.z; v.w += bv.w;
            }
            *reinterpret_cast<float4*>(&out[(long)row * CH + col]) = v;
        }
    }
}

// ---------------- E0-graph GCN aggregation via CSR (f64 acc) ----------------
__global__ __launch_bounds__(256) void agg_e0(
    const float* __restrict__ h, const int* __restrict__ rowptr,
    const int* __restrict__ colsrc, const double* __restrict__ inv,
    const float* __restrict__ bias, float* __restrict__ out, int n)
{
    __shared__ int s_src[256];
    __shared__ double s_nrm[256];
    int i = blockIdx.x, c = threadIdx.x;
    int r0 = rowptr[i], r1 = rowptr[i + 1];
    double invd = inv[i];
    double acc = (double)h[(long)i * CH + c] * (invd * invd);  // self loop
    for (int base = r0; base < r1; base += 256) {
        int m = min(256, r1 - base);
        __syncthreads();
        if (c < m) {
            int s = colsrc[base + c];
            s_src[c] = s;
            s_nrm[c] = invd * inv[s];
        }
        __syncthreads();
        for (int j = 0; j < m; ++j)
            acc += (double)h[(long)s_src[j] * CH + c] * s_nrm[j];
    }
    double v = acc + (double)bias[c];
    out[(long)i * CH + c] = (float)fmax(v, 0.0);
}

// ---------------- KNN-graph aggregation: mean over (k neighbors + self), f64 acc ----------------
__global__ void agg_knn(const float* __restrict__ h, const int* __restrict__ idx,
                        const float* __restrict__ b, float* __restrict__ out,
                        int n, int k, double s) {
    int i = blockIdx.x, c = threadIdx.x;
    double acc = (double)h[(long)i * CH + c];
    for (int j = 0; j < k; ++j) {
        int nb = idx[i * k + j];
        acc += (double)h[(long)nb * CH + c];
    }
    double v = acc * s + (double)b[c];
    out[(long)i * CH + c] = (float)fmax(v, 0.0);
}

// ---------------- grid-bucket exact KNN (FROZEN since R16 — matches golden) ----------------
__global__ void cell_count(const float* __restrict__ pos, int n, int G, int* __restrict__ cnt) {
    int i = blockIdx.x * blockDim.x + threadIdx.x;
    if (i < n) {
        float2 p = ((const float2*)pos)[i];
        int cx = min(G - 1, (int)(p.x * G));
        int cy = min(G - 1, (int)(p.y * G));
        atomicAdd(&cnt[cy * G + cx], 1);
    }
}
__global__ void cell_fill(const float* __restrict__ pos, int n, int G, int* __restrict__ cur,
                          float2* __restrict__ cpos, int* __restrict__ cidx) {
    int i = blockIdx.x * blockDim.x + threadIdx.x;
    if (i < n) {
        float2 p = ((const float2*)pos)[i];
        int cx = min(G - 1, (int)(p.x * G));
        int cy = min(G - 1, (int)(p.y * G));
        int t = atomicAdd(&cur[cy * G + cx], 1);
        cpos[t] = p;
        cidx[t] = i;
    }
}

template <int K>
__global__ void knn_grid(const float* __restrict__ pos, int n, int G,
                         const int* __restrict__ cellptr,
                         const float2* __restrict__ cpos,
                         const int* __restrict__ cidx,
                         int* __restrict__ outIdx) {
    int t0 = blockIdx.x * blockDim.x + threadIdx.x;
    if (t0 >= n) return;
    int q = cidx[t0];                       // cell-sorted query order
    const float INF = __int_as_float(0x7f800000);
    const float EPS = 1e-5f;
    float h = 1.0f / (float)G;
    float2 qp = cpos[t0];                   // == pos[q]
    float sqq = __fmaf_rn(qp.y, qp.y, __fmul_rn(qp.x, qp.x));
    int cx = min(G - 1, (int)(qp.x * G));
    int cy = min(G - 1, (int)(qp.y * G));
    float bd[K];
    int bi[K];
#pragma unroll
    for (int t = 0; t < K; ++t) { bd[t] = INF; bi[t] = 0x7fffffff; }

    auto visit = [&](int xx, int yy) {
        int ci = yy * G + xx;
        int s = cellptr[ci], e = cellptr[ci + 1];
        for (int t = s; t < e; ++t) {
            float2 pj = cpos[t];
            int j = cidx[t];
            float sqj = __fmaf_rn(pj.y, pj.y, __fmul_rn(pj.x, pj.x));
            float dot = __fmaf_rn(qp.y, pj.y, __fmul_rn(qp.x, pj.x));
            float t1  = __fadd_rn(sqq, sqj);
            float d   = __fmaf_rn(-2.0f, dot, t1);
            if (j == q) continue;
            if (d < bd[K - 1] || (d == bd[K - 1] && j < bi[K - 1])) {
                bd[K - 1] = d; bi[K - 1] = j;
#pragma unroll
                for (int t2 = K - 1; t2 > 0; --t2) {
                    bool sw = (bd[t2] < bd[t2 - 1]) ||
                              (bd[t2] == bd[t2 - 1] && bi[t2] < bi[t2 - 1]);
                    if (sw) {
                        float td = bd[t2]; bd[t2] = bd[t2 - 1]; bd[t2 - 1] = td;
                        int ti = bi[t2]; bi[t2] = bi[t2 - 1]; bi[t2 - 1] = ti;
                    }
                }
            }
        }
    };

    for (int c = 0; c < G; ++c) {
        if (c > 0 && bi[K - 1] != 0x7fffffff) {
            float lim = (float)(c - 1) * h;
            if (lim * lim > bd[K - 1] + EPS) break;
        }
        int y0 = max(0, cy - c), y1 = min(G - 1, cy + c);
        for (int yy = y0; yy <= y1; ++yy) {
            if (yy == cy - c || yy == cy + c) {
                int x0 = max(0, cx - c), x1 = min(G - 1, cx + c);
                for (int xx = x0; xx <= x1; ++xx) visit(xx, yy);
            } else {
                if (cx - c >= 0) visit(cx - c, yy);
                if (cx + c <= G - 1) visit(cx + c, yy);
            }
        }
    }
#pragma unroll
    for (int r = 0; r < K; ++r) outIdx[q * K + r] = bi[r];
}

// ---------------- gathers / scatters ----------------
__global__ void gather_pos(const float* __restrict__ pos, const int* __restrict__ perm,
                           float* __restrict__ out, int m) {
    int i = blockIdx.x * blockDim.x + threadIdx.x;
    if (i < m) {
        int p = perm[i];
        ((float2*)out)[i] = ((const float2*)pos)[p];
    }
}
__global__ void copy_rows(const float* __restrict__ srcb, const int* __restrict__ perm,
                          float* __restrict__ dst, int m) {
    int i = blockIdx.x, c = threadIdx.x;
    int r = perm[i];
    dst[(long)r * CH + c] = srcb[(long)r * CH + c];
}
__global__ void scatter_rows(const float* __restrict__ srcb, const int* __restrict__ perm,
                             float* __restrict__ dst, int m) {
    int i = blockIdx.x, c = threadIdx.x;
    dst[(long)perm[i] * CH + c] = srcb[(long)i * CH + c];
}

extern "C" void kernel_launch(void* const* d_in, const int* in_sizes, int n_in,
                              void* d_out, int out_size, void* d_ws, size_t ws_size,
                              hipStream_t stream) {
    const float* x    = (const float*)d_in[0];
    const float* pos  = (const float*)d_in[1];
    const int*   ei   = (const int*)d_in[2];   // [2, E0]: src = ei[0:E0), dst = ei[E0:2E0)
    const int*   perm1 = (const int*)d_in[3];
    const int*   perm2 = (const int*)d_in[4];
    const int*   perm3 = (const int*)d_in[5];
    const float* Wd0 = (const float*)d_in[6],  *bd0 = (const float*)d_in[7];
    const float* Wd1 = (const float*)d_in[8],  *bd1 = (const float*)d_in[9];
    const float* Wd2 = (const float*)d_in[10], *bd2 = (const float*)d_in[11];
    const float* Wu0 = (const float*)d_in[12], *bu0 = (const float*)d_in[13];
    const float* Wu1 = (const float*)d_in[14], *bu1 = (const float*)d_in[15];
    const float* Wu2 = (const float*)d_in[16], *bu2 = (const float*)d_in[17];
    const float* Wlin = (const float*)d_in[18], *blin = (const float*)d_in[19];
    float* out = (float*)d_out;  // doubles as scratch B (fully rewritten every call)

    // workspace carve
    double* inv0 = (double*)d_ws;                 // N0 doubles
    float* pos1 = (float*)(inv0 + N0);            // N1*2 floats
    float* pos2 = pos1 + N1 * 2;                  // N2*2 floats
    float* A   = pos2 + N2 * 2;                   // N0*CH
    float* C_  = A + (long)N0 * CH;               // N1*CH
    float* D_  = C_ + (long)N1 * CH;              // N1*CH
    int* degI   = (int*)(D_ + (long)N1 * CH);     // N0
    int* rowptr = degI + N0;                      // N0+1
    int* cursor = rowptr + N0 + 1;                // N0
    int* colsrc = cursor + N0;                    // E0
    int* idx1   = colsrc + E0;                    // N1*6
    int* idx2   = idx1 + N1 * 6;                  // N2*7
    int* incl   = idx2 + N2 * 7;                  // N0 (scan stage buffer; reused for cell scans)
    int* bsum   = incl + N0;                      // NBLK
    int* cellcnt = bsum + NBLK;                   // 4096
    int* cellptr = cellcnt + 4096;                // 4097
    int* ccur    = cellptr + 4097;                // 4096
    int* cellidx = ccur + 4096;                   // N1
    float2* cellpos = (float2*)(((uintptr_t)(cellidx + N1) + 15) & ~(uintptr_t)15);  // N1 float2
    float* B = out;

    const int* e_src = ei;
    const int* e_dst = ei + E0;

    // ---- CSR + norms for the input graph ----
    hipMemsetAsync(degI, 0, (size_t)N0 * sizeof(int), stream);
    count_deg<<<(E0 + 255) / 256, 256, 0, stream>>>(e_dst, degI, E0);
    scan_blocks<<<NBLK, 256, 0, stream>>>(degI, incl, bsum, N0);
    scan_bsums<<<1, 256, 0, stream>>>(bsum, NBLK);
    finalize_rowptr<<<(N0 + 255) / 256, 256, 0, stream>>>(incl, bsum, rowptr, N0);
    copy_int<<<(N0 + 255) / 256, 256, 0, stream>>>(rowptr, cursor, N0);
    fill_csr<<<(E0 + 255) / 256, 256, 0, stream>>>(e_src, e_dst, cursor, colsrc, E0);
    make_inv<<<(N0 + 255) / 256, 256, 0, stream>>>(degI, inv0, N0);

    // ---- encoder level 0: conv(E0 graph) + relu ----
    gemm_f32<<<(N0 + 63) / 64, 256, 0, stream>>>(x, nullptr, Wd0, nullptr, A, N0, CIN);
    agg_e0<<<N0, 256, 0, stream>>>(A, rowptr, colsrc, inv0, bd0, B, N0);

    // ---- KNN level 1 (grid G=64, cell-sorted queries) ----
    gather_pos<<<(N1 + 255) / 256, 256, 0, stream>>>(pos, perm1, pos1, N1);
    {
        const int G1 = 64, NC1 = G1 * G1;  // 4096 cells, ~2.4 pts/cell
        hipMemsetAsync(cellcnt, 0, (size_t)NC1 * sizeof(int), stream);
        cell_count<<<(N1 + 255) / 256, 256, 0, stream>>>(pos1, N1, G1, cellcnt);
        scan_blocks<<<NC1 / 256, 256, 0, stream>>>(cellcnt, incl, bsum, NC1);
        scan_bsums<<<1, 256, 0, stream>>>(bsum, NC1 / 256);
        finalize_rowptr<<<(NC1 + 255) / 256, 256, 0, stream>>>(incl, bsum, cellptr, NC1);
        copy_int<<<(NC1 + 255) / 256, 256, 0, stream>>>(cellptr, ccur, NC1);
        cell_fill<<<(N1 + 255) / 256, 256, 0, stream>>>(pos1, N1, G1, ccur, cellpos, cellidx);
        knn_grid<6><<<(N1 + 255) / 256, 256, 0, stream>>>(pos1, N1, G1, cellptr, cellpos, cellidx, idx1);
    }

    // ---- encoder level 1 (pool via gather) ----
    gemm_f32<<<(N1 + 63) / 64, 256, 0, stream>>>(B, perm1, Wd1, nullptr, C_, N1, CH);
    agg_knn<<<N1, 256, 0, stream>>>(C_, idx1, bd1, D_, N1, 6, 1.0 / 7.0);

    // ---- KNN level 2 (grid G=32, cell-sorted queries) ----
    gather_pos<<<(N2 + 255) / 256, 256, 0, stream>>>(pos1, perm2, pos2, N2);
    {
        const int G2 = 32, NC2 = G2 * G2;  // 1024 cells, ~2.4 pts/cell
        hipMemsetAsync(cellcnt, 0, (size_t)NC2 * sizeof(int), stream);
        cell_count<<<(N2 + 255) / 256, 256, 0, stream>>>(pos2, N2, G2, cellcnt);
        scan_blocks<<<NC2 / 256, 256, 0, stream>>>(cellcnt, incl, bsum, NC2);
        scan_bsums<<<1, 256, 0, stream>>>(bsum, NC2 / 256);
        finalize_rowptr<<<(NC2 + 255) / 256, 256, 0, stream>>>(incl, bsum, cellptr, NC2);
        copy_int<<<(NC2 + 255) / 256, 256, 0, stream>>>(cellptr, ccur, NC2);
        cell_fill<<<(N2 + 255) / 256, 256, 0, stream>>>(pos2, N2, G2, ccur, cellpos, cellidx);
        knn_grid<7><<<(N2 + 255) / 256, 256, 0, stream>>>(pos2, N2, G2, cellptr, cellpos, cellidx, idx2);
    }

    // ---- encoder level 2 ----
    gemm_f32<<<(N2 + 63) / 64, 256, 0, stream>>>(D_, perm2, Wd2, nullptr, C_, N2, CH);
    agg_knn<<<N2, 256, 0, stream>>>(C_, idx2, bd2, D_, N2, 7, 1.0 / 8.0);  // Y2 in D_[0:N2)

    // ---- decoder level 0 (N2 nodes, knn2 graph): mask rows perm3 ----
    hipMemsetAsync(C_, 0, (size_t)N2 * CH * sizeof(float), stream);
    copy_rows<<<N3, 256, 0, stream>>>(D_, perm3, C_, N3);
    gemm_f32<<<(N2 + 63) / 64, 256, 0, stream>>>(C_, nullptr, Wu0, nullptr, D_, N2, CH);
    agg_knn<<<N2, 256, 0, stream>>>(D_, idx2, bu0, C_, N2, 7, 1.0 / 8.0);

    // ---- decoder level 1 (N1 nodes, knn1 graph) ----
    hipMemsetAsync(D_, 0, (size_t)N1 * CH * sizeof(float), stream);
    scatter_rows<<<N2, 256, 0, stream>>>(C_, perm2, D_, N2);
    gemm_f32<<<(N1 + 63) / 64, 256, 0, stream>>>(D_, nullptr, Wu1, nullptr, C_, N1, CH);
    agg_knn<<<N1, 256, 0, stream>>>(C_, idx1, bu1, D_, N1, 6, 1.0 / 7.0);

    // ---- decoder level 2 (N0 nodes, E0 graph) ----
    hipMemsetAsync(A, 0, (size_t)N0 * CH * sizeof(float), stream);
    scatter_rows<<<N1, 256, 0, stream>>>(D_, perm1, A, N1);
    gemm_f32<<<(N0 + 63) / 64, 256, 0, stream>>>(A, nullptr, Wu2, nullptr, B, N0, CH);
    agg_e0<<<N0, 256, 0, stream>>>(B, rowptr, colsrc, inv0, bu2, A, N0);

    // ---- final linear ----
    gemm_f32<<<(N0 + 63) / 64, 256, 0, stream>>>(A, nullptr, Wlin, blin, out, N0, CH);
}

// Round 18
// 675.981 us; speedup vs baseline: 1.1320x; 1.1320x over previous
//
#include <hip/hip_runtime.h>
#include <hip/hip_bf16.h>
#include <stdint.h>

#define N0 40000
#define N1 10000
#define N2 2500
#define N3 625
#define E0 240000
#define CIN 64
#define CH 256
#define NBLK ((N0 + 255) / 256)   // 157 scan blocks

// ---------------- degree / CSR build ----------------
__global__ void count_deg(const int* __restrict__ dst, int* __restrict__ deg, int e) {
    int i = blockIdx.x * blockDim.x + threadIdx.x;
    if (i < e) atomicAdd(&deg[dst[i]], 1);
}

__global__ __launch_bounds__(256) void scan_blocks(const int* __restrict__ deg,
                                                   int* __restrict__ incl,
                                                   int* __restrict__ bsum, int n) {
    __shared__ int s[256];
    int i = blockIdx.x * 256 + threadIdx.x;
    s[threadIdx.x] = (i < n) ? deg[i] : 0;
    __syncthreads();
#pragma unroll
    for (int off = 1; off < 256; off <<= 1) {
        int t = (threadIdx.x >= off) ? s[threadIdx.x - off] : 0;
        __syncthreads();
        s[threadIdx.x] += t;
        __syncthreads();
    }
    if (i < n) incl[i] = s[threadIdx.x];
    if (threadIdx.x == 255) bsum[blockIdx.x] = s[255];
}

__global__ __launch_bounds__(256) void scan_bsums(int* __restrict__ bsum, int nb) {
    __shared__ int s[256];
    s[threadIdx.x] = (threadIdx.x < nb) ? bsum[threadIdx.x] : 0;
    __syncthreads();
#pragma unroll
    for (int off = 1; off < 256; off <<= 1) {
        int t = (threadIdx.x >= off) ? s[threadIdx.x - off] : 0;
        __syncthreads();
        s[threadIdx.x] += t;
        __syncthreads();
    }
    if (threadIdx.x < nb) bsum[threadIdx.x] = s[threadIdx.x];
}

__global__ void finalize_rowptr(const int* __restrict__ incl, const int* __restrict__ bsum,
                                int* __restrict__ rowptr, int n) {
    int i = blockIdx.x * blockDim.x + threadIdx.x;
    if (i == 0) rowptr[0] = 0;
    if (i < n) {
        int b = i >> 8;
        int off = b ? bsum[b - 1] : 0;
        rowptr[i + 1] = incl[i] + off;
    }
}

__global__ void copy_int(const int* __restrict__ a, int* __restrict__ b, int n) {
    int i = blockIdx.x * blockDim.x + threadIdx.x;
    if (i < n) b[i] = a[i];
}
__global__ void fill_csr(const int* __restrict__ src, const int* __restrict__ dst,
                         int* __restrict__ cursor, int* __restrict__ colsrc, int e) {
    int i = blockIdx.x * blockDim.x + threadIdx.x;
    if (i < e) {
        int d = dst[i];
        int p = atomicAdd(&cursor[d], 1);
        colsrc[p] = src[i];
    }
}
__global__ void make_inv(const int* __restrict__ deg, double* __restrict__ inv, int n) {
    int i = blockIdx.x * blockDim.x + threadIdx.x;
    if (i < n) inv[i] = 1.0 / sqrt((double)(deg[i] + 1));  // +1 self loop
}

// ---------------- f32 GEMM: block = 64 rows x 128 cols (A refetch 2x, grid 2x R17) ----------------
// out[M x 256] = A[gidx[M] x K] @ W[K x 256] (+bias). Per-output k-accumulation order unchanged.
__global__ __launch_bounds__(256) void gemm_f32(
    const float* __restrict__ A, const int* __restrict__ gidx,
    const float* __restrict__ W, const float* __restrict__ bias,
    float* __restrict__ out, int M, int K)
{
    __shared__ float As[16][68];    // [k][row]
    __shared__ float Bs[16][132];   // [k][col 0..127]; stride%32=4 breaks bank powers
    const int tid = threadIdx.x;
    const int tx = tid & 15, ty = tid >> 4;
    const int row0 = blockIdx.x * 64, col0 = blockIdx.y * 128;
    const int sr = tid >> 2;            // 0..63 (row for A staging)
    const int skq = (tid & 3) * 4;      // k-quad for A staging
    const int bkk = tid >> 4;           // 0..15 (k-row for B staging)
    const int bc4 = (tid & 15) * 4;     // col-quad base for B staging
    const int arow = row0 + sr;
    const bool rowok = arow < M;
    long arr = 0;
    if (rowok) arr = (long)(gidx ? gidx[arow] : arow) * K;

    float acc[4][8] = {};  // [row i][col = q*4+j]
    for (int k0 = 0; k0 < K; k0 += 16) {
        float4 av = make_float4(0.f, 0.f, 0.f, 0.f);
        if (rowok) av = *reinterpret_cast<const float4*>(&A[arr + k0 + skq]);
        As[skq + 0][sr] = av.x;
        As[skq + 1][sr] = av.y;
        As[skq + 2][sr] = av.z;
        As[skq + 3][sr] = av.w;
#pragma unroll
        for (int q = 0; q < 2; ++q) {
            float4 bv = *reinterpret_cast<const float4*>(&W[(long)(k0 + bkk) * CH + col0 + q * 64 + bc4]);
            *reinterpret_cast<float4*>(&Bs[bkk][q * 64 + bc4]) = bv;
        }
        __syncthreads();
#pragma unroll
        for (int kk = 0; kk < 16; ++kk) {
            float4 a4 = *reinterpret_cast<const float4*>(&As[kk][ty * 4]);
            float a[4] = {a4.x, a4.y, a4.z, a4.w};
            float b[8];
#pragma unroll
            for (int q = 0; q < 2; ++q) {
                float4 b4 = *reinterpret_cast<const float4*>(&Bs[kk][q * 64 + tx * 4]);
                b[q * 4 + 0] = b4.x; b[q * 4 + 1] = b4.y;
                b[q * 4 + 2] = b4.z; b[q * 4 + 3] = b4.w;
            }
#pragma unroll
            for (int i = 0; i < 4; i++)
#pragma unroll
                for (int j = 0; j < 8; j++) acc[i][j] += a[i] * b[j];
        }
        __syncthreads();
    }
#pragma unroll
    for (int i = 0; i < 4; i++) {
        int row = row0 + ty * 4 + i;
        if (row >= M) continue;
#pragma unroll
        for (int q = 0; q < 2; ++q) {
            int col = col0 + q * 64 + tx * 4;
            float4 v = make_float4(acc[i][q * 4 + 0], acc[i][q * 4 + 1],
                                   acc[i][q * 4 + 2], acc[i][q * 4 + 3]);
            if (bias) {
                float4 bv = *reinterpret_cast<const float4*>(&bias[col]);
                v.x += bv.x; v.y += bv.y; v.z += bv.z; v.w += bv.w;
            }
            *reinterpret_cast<float4*>(&out[(long)row * CH + col]) = v;
        }
    }
}

// ---------------- E0-graph GCN aggregation via CSR (f64 acc) ----------------
__global__ __launch_bounds__(256) void agg_e0(
    const float* __restrict__ h, const int* __restrict__ rowptr,
    const int* __restrict__ colsrc, const double* __restrict__ inv,
    const float* __restrict__ bias, float* __restrict__ out, int n)
{
    __shared__ int s_src[256];
    __shared__ double s_nrm[256];
    int i = blockIdx.x, c = threadIdx.x;
    int r0 = rowptr[i], r1 = rowptr[i + 1];
    double invd = inv[i];
    double acc = (double)h[(long)i * CH + c] * (invd * invd);  // self loop
    for (int base = r0; base < r1; base += 256) {
        int m = min(256, r1 - base);
        __syncthreads();
        if (c < m) {
            int s = colsrc[base + c];
            s_src[c] = s;
            s_nrm[c] = invd * inv[s];
        }
        __syncthreads();
        for (int j = 0; j < m; ++j)
            acc += (double)h[(long)s_src[j] * CH + c] * s_nrm[j];
    }
    double v = acc + (double)bias[c];
    out[(long)i * CH + c] = (float)fmax(v, 0.0);
}

// ---------------- KNN-graph aggregation: mean over (k neighbors + self), f64 acc ----------------
__global__ void agg_knn(const float* __restrict__ h, const int* __restrict__ idx,
                        const float* __restrict__ b, float* __restrict__ out,
                        int n, int k, double s) {
    int i = blockIdx.x, c = threadIdx.x;
    double acc = (double)h[(long)i * CH + c];
    for (int j = 0; j < k; ++j) {
        int nb = idx[i * k + j];
        acc += (double)h[(long)nb * CH + c];
    }
    double v = acc * s + (double)b[c];
    out[(long)i * CH + c] = (float)fmax(v, 0.0);
}

// ---------------- grid-bucket exact KNN (FROZEN since R16 — matches golden) ----------------
__global__ void cell_count(const float* __restrict__ pos, int n, int G, int* __restrict__ cnt) {
    int i = blockIdx.x * blockDim.x + threadIdx.x;
    if (i < n) {
        float2 p = ((const float2*)pos)[i];
        int cx = min(G - 1, (int)(p.x * G));
        int cy = min(G - 1, (int)(p.y * G));
        atomicAdd(&cnt[cy * G + cx], 1);
    }
}
__global__ void cell_fill(const float* __restrict__ pos, int n, int G, int* __restrict__ cur,
                          float2* __restrict__ cpos, int* __restrict__ cidx) {
    int i = blockIdx.x * blockDim.x + threadIdx.x;
    if (i < n) {
        float2 p = ((const float2*)pos)[i];
        int cx = min(G - 1, (int)(p.x * G));
        int cy = min(G - 1, (int)(p.y * G));
        int t = atomicAdd(&cur[cy * G + cx], 1);
        cpos[t] = p;
        cidx[t] = i;
    }
}

template <int K>
__global__ void knn_grid(const float* __restrict__ pos, int n, int G,
                         const int* __restrict__ cellptr,
                         const float2* __restrict__ cpos,
                         const int* __restrict__ cidx,
                         int* __restrict__ outIdx) {
    int t0 = blockIdx.x * blockDim.x + threadIdx.x;
    if (t0 >= n) return;
    int q = cidx[t0];                       // cell-sorted query order
    const float INF = __int_as_float(0x7f800000);
    const float EPS = 1e-5f;
    float h = 1.0f / (float)G;
    float2 qp = cpos[t0];                   // == pos[q]
    float sqq = __fmaf_rn(qp.y, qp.y, __fmul_rn(qp.x, qp.x));
    int cx = min(G - 1, (int)(qp.x * G));
    int cy = min(G - 1, (int)(qp.y * G));
    float bd[K];
    int bi[K];
#pragma unroll
    for (int t = 0; t < K; ++t) { bd[t] = INF; bi[t] = 0x7fffffff; }

    auto visit = [&](int xx, int yy) {
        int ci = yy * G + xx;
        int s = cellptr[ci], e = cellptr[ci + 1];
        for (int t = s; t < e; ++t) {
            float2 pj = cpos[t];
            int j = cidx[t];
            float sqj = __fmaf_rn(pj.y, pj.y, __fmul_rn(pj.x, pj.x));
            float dot = __fmaf_rn(qp.y, pj.y, __fmul_rn(qp.x, pj.x));
            float t1  = __fadd_rn(sqq, sqj);
            float d   = __fmaf_rn(-2.0f, dot, t1);
            if (j == q) continue;
            if (d < bd[K - 1] || (d == bd[K - 1] && j < bi[K - 1])) {
                bd[K - 1] = d; bi[K - 1] = j;
#pragma unroll
                for (int t2 = K - 1; t2 > 0; --t2) {
                    bool sw = (bd[t2] < bd[t2 - 1]) ||
                              (bd[t2] == bd[t2 - 1] && bi[t2] < bi[t2 - 1]);
                    if (sw) {
                        float td = bd[t2]; bd[t2] = bd[t2 - 1]; bd[t2 - 1] = td;
                        int ti = bi[t2]; bi[t2] = bi[t2 - 1]; bi[t2 - 1] = ti;
                    }
                }
            }
        }
    };

    for (int c = 0; c < G; ++c) {
        if (c > 0 && bi[K - 1] != 0x7fffffff) {
            float lim = (float)(c - 1) * h;
            if (lim * lim > bd[K - 1] + EPS) break;
        }
        int y0 = max(0, cy - c), y1 = min(G - 1, cy + c);
        for (int yy = y0; yy <= y1; ++yy) {
            if (yy == cy - c || yy == cy + c) {
                int x0 = max(0, cx - c), x1 = min(G - 1, cx + c);
                for (int xx = x0; xx <= x1; ++xx) visit(xx, yy);
            } else {
                if (cx - c >= 0) visit(cx - c, yy);
                if (cx + c <= G - 1) visit(cx + c, yy);
            }
        }
    }
#pragma unroll
    for (int r = 0; r < K; ++r) outIdx[q * K + r] = bi[r];
}

// ---------------- gathers / scatters ----------------
__global__ void gather_pos(const float* __restrict__ pos, const int* __restrict__ perm,
                           float* __restrict__ out, int m) {
    int i = blockIdx.x * blockDim.x + threadIdx.x;
    if (i < m) {
        int p = perm[i];
        ((float2*)out)[i] = ((const float2*)pos)[p];
    }
}
__global__ void copy_rows(const float* __restrict__ srcb, const int* __restrict__ perm,
                          float* __restrict__ dst, int m) {
    int i = blockIdx.x, c = threadIdx.x;
    int r = perm[i];
    dst[(long)r * CH + c] = srcb[(long)r * CH + c];
}
__global__ void scatter_rows(const float* __restrict__ srcb, const int* __restrict__ perm,
                             float* __restrict__ dst, int m) {
    int i = blockIdx.x, c = threadIdx.x;
    dst[(long)perm[i] * CH + c] = srcb[(long)i * CH + c];
}

extern "C" void kernel_launch(void* const* d_in, const int* in_sizes, int n_in,
                              void* d_out, int out_size, void* d_ws, size_t ws_size,
                              hipStream_t stream) {
    const float* x    = (const float*)d_in[0];
    const float* pos  = (const float*)d_in[1];
    const int*   ei   = (const int*)d_in[2];   // [2, E0]: src = ei[0:E0), dst = ei[E0:2E0)
    const int*   perm1 = (const int*)d_in[3];
    const int*   perm2 = (const int*)d_in[4];
    const int*   perm3 = (const int*)d_in[5];
    const float* Wd0 = (const float*)d_in[6],  *bd0 = (const float*)d_in[7];
    const float* Wd1 = (const float*)d_in[8],  *bd1 = (const float*)d_in[9];
    const float* Wd2 = (const float*)d_in[10], *bd2 = (const float*)d_in[11];
    const float* Wu0 = (const float*)d_in[12], *bu0 = (const float*)d_in[13];
    const float* Wu1 = (const float*)d_in[14], *bu1 = (const float*)d_in[15];
    const float* Wu2 = (const float*)d_in[16], *bu2 = (const float*)d_in[17];
    const float* Wlin = (const float*)d_in[18], *blin = (const float*)d_in[19];
    float* out = (float*)d_out;  // doubles as scratch B (fully rewritten every call)

    // workspace carve
    double* inv0 = (double*)d_ws;                 // N0 doubles
    float* pos1 = (float*)(inv0 + N0);            // N1*2 floats
    float* pos2 = pos1 + N1 * 2;                  // N2*2 floats
    float* A   = pos2 + N2 * 2;                   // N0*CH
    float* C_  = A + (long)N0 * CH;               // N1*CH
    float* D_  = C_ + (long)N1 * CH;              // N1*CH
    int* degI   = (int*)(D_ + (long)N1 * CH);     // N0
    int* rowptr = degI + N0;                      // N0+1
    int* cursor = rowptr + N0 + 1;                // N0
    int* colsrc = cursor + N0;                    // E0
    int* idx1   = colsrc + E0;                    // N1*6
    int* idx2   = idx1 + N1 * 6;                  // N2*7
    int* incl   = idx2 + N2 * 7;                  // N0 (scan stage buffer; reused for cell scans)
    int* bsum   = incl + N0;                      // NBLK
    int* cellcnt = bsum + NBLK;                   // 4096
    int* cellptr = cellcnt + 4096;                // 4097
    int* ccur    = cellptr + 4097;                // 4096
    int* cellidx = ccur + 4096;                   // N1
    float2* cellpos = (float2*)(((uintptr_t)(cellidx + N1) + 15) & ~(uintptr_t)15);  // N1 float2
    float* B = out;

    const int* e_src = ei;
    const int* e_dst = ei + E0;

    // ---- CSR + norms for the input graph ----
    hipMemsetAsync(degI, 0, (size_t)N0 * sizeof(int), stream);
    count_deg<<<(E0 + 255) / 256, 256, 0, stream>>>(e_dst, degI, E0);
    scan_blocks<<<NBLK, 256, 0, stream>>>(degI, incl, bsum, N0);
    scan_bsums<<<1, 256, 0, stream>>>(bsum, NBLK);
    finalize_rowptr<<<(N0 + 255) / 256, 256, 0, stream>>>(incl, bsum, rowptr, N0);
    copy_int<<<(N0 + 255) / 256, 256, 0, stream>>>(rowptr, cursor, N0);
    fill_csr<<<(E0 + 255) / 256, 256, 0, stream>>>(e_src, e_dst, cursor, colsrc, E0);
    make_inv<<<(N0 + 255) / 256, 256, 0, stream>>>(degI, inv0, N0);

    // ---- encoder level 0: conv(E0 graph) + relu ----
    gemm_f32<<<dim3((N0 + 63) / 64, 2), 256, 0, stream>>>(x, nullptr, Wd0, nullptr, A, N0, CIN);
    agg_e0<<<N0, 256, 0, stream>>>(A, rowptr, colsrc, inv0, bd0, B, N0);

    // ---- KNN level 1 (grid G=64, cell-sorted queries) ----
    gather_pos<<<(N1 + 255) / 256, 256, 0, stream>>>(pos, perm1, pos1, N1);
    {
        const int G1 = 64, NC1 = G1 * G1;  // 4096 cells, ~2.4 pts/cell
        hipMemsetAsync(cellcnt, 0, (size_t)NC1 * sizeof(int), stream);
        cell_count<<<(N1 + 255) / 256, 256, 0, stream>>>(pos1, N1, G1, cellcnt);
        scan_blocks<<<NC1 / 256, 256, 0, stream>>>(cellcnt, incl, bsum, NC1);
        scan_bsums<<<1, 256, 0, stream>>>(bsum, NC1 / 256);
        finalize_rowptr<<<(NC1 + 255) / 256, 256, 0, stream>>>(incl, bsum, cellptr, NC1);
        copy_int<<<(NC1 + 255) / 256, 256, 0, stream>>>(cellptr, ccur, NC1);
        cell_fill<<<(N1 + 255) / 256, 256, 0, stream>>>(pos1, N1, G1, ccur, cellpos, cellidx);
        knn_grid<6><<<(N1 + 255) / 256, 256, 0, stream>>>(pos1, N1, G1, cellptr, cellpos, cellidx, idx1);
    }

    // ---- encoder level 1 (pool via gather) ----
    gemm_f32<<<dim3((N1 + 63) / 64, 2), 256, 0, stream>>>(B, perm1, Wd1, nullptr, C_, N1, CH);
    agg_knn<<<N1, 256, 0, stream>>>(C_, idx1, bd1, D_, N1, 6, 1.0 / 7.0);

    // ---- KNN level 2 (grid G=32, cell-sorted queries) ----
    gather_pos<<<(N2 + 255) / 256, 256, 0, stream>>>(pos1, perm2, pos2, N2);
    {
        const int G2 = 32, NC2 = G2 * G2;  // 1024 cells, ~2.4 pts/cell
        hipMemsetAsync(cellcnt, 0, (size_t)NC2 * sizeof(int), stream);
        cell_count<<<(N2 + 255) / 256, 256, 0, stream>>>(pos2, N2, G2, cellcnt);
        scan_blocks<<<NC2 / 256, 256, 0, stream>>>(cellcnt, incl, bsum, NC2);
        scan_bsums<<<1, 256, 0, stream>>>(bsum, NC2 / 256);
        finalize_rowptr<<<(NC2 + 255) / 256, 256, 0, stream>>>(incl, bsum, cellptr, NC2);
        copy_int<<<(NC2 + 255) / 256, 256, 0, stream>>>(cellptr, ccur, NC2);
        cell_fill<<<(N2 + 255) / 256, 256, 0, stream>>>(pos2, N2, G2, ccur, cellpos, cellidx);
        knn_grid<7><<<(N2 + 255) / 256, 256, 0, stream>>>(pos2, N2, G2, cellptr, cellpos, cellidx, idx2);
    }

    // ---- encoder level 2 ----
    gemm_f32<<<dim3((N2 + 63) / 64, 2), 256, 0, stream>>>(D_, perm2, Wd2, nullptr, C_, N2, CH);
    agg_knn<<<N2, 256, 0, stream>>>(C_, idx2, bd2, D_, N2, 7, 1.0 / 8.0);  // Y2 in D_[0:N2)

    // ---- decoder level 0 (N2 nodes, knn2 graph): mask rows perm3 ----
    hipMemsetAsync(C_, 0, (size_t)N2 * CH * sizeof(float), stream);
    copy_rows<<<N3, 256, 0, stream>>>(D_, perm3, C_, N3);
    gemm_f32<<<dim3((N2 + 63) / 64, 2), 256, 0, stream>>>(C_, nullptr, Wu0, nullptr, D_, N2, CH);
    agg_knn<<<N2, 256, 0, stream>>>(D_, idx2, bu0, C_, N2, 7, 1.0 / 8.0);

    // ---- decoder level 1 (N1 nodes, knn1 graph) ----
    hipMemsetAsync(D_, 0, (size_t)N1 * CH * sizeof(float), stream);
    scatter_rows<<<N2, 256, 0, stream>>>(C_, perm2, D_, N2);
    gemm_f32<<<dim3((N1 + 63) / 64, 2), 256, 0, stream>>>(D_, nullptr, Wu1, nullptr, C_, N1, CH);
    agg_knn<<<N1, 256, 0, stream>>>(C_, idx1, bu1, D_, N1, 6, 1.0 / 7.0);

    // ---- decoder level 2 (N0 nodes, E0 graph) ----
    hipMemsetAsync(A, 0, (size_t)N0 * CH * sizeof(float), stream);
    scatter_rows<<<N1, 256, 0, stream>>>(D_, perm1, A, N1);
    gemm_f32<<<dim3((N0 + 63) / 64, 2), 256, 0, stream>>>(A, nullptr, Wu2, nullptr, B, N0, CH);
    agg_e0<<<N0, 256, 0, stream>>>(B, rowptr, colsrc, inv0, bu2, A, N0);

    // ---- final linear ----
    gemm_f32<<<dim3((N0 + 63) / 64, 2), 256, 0, stream>>>(A, nullptr, Wlin, blin, out, N0, CH);
}

// Round 19
// 640.323 us; speedup vs baseline: 1.1950x; 1.0557x over previous
//
#include <hip/hip_runtime.h>
#include <hip/hip_bf16.h>
#include <stdint.h>

#define N0 40000
#define N1 10000
#define N2 2500
#define N3 625
#define E0 240000
#define CIN 64
#define CH 256
#define NBLK ((N0 + 255) / 256)   // 157 scan blocks

// ---------------- degree / CSR build ----------------
__global__ void count_deg(const int* __restrict__ dst, int* __restrict__ deg, int e) {
    int i = blockIdx.x * blockDim.x + threadIdx.x;
    if (i < e) atomicAdd(&deg[dst[i]], 1);
}

__global__ __launch_bounds__(256) void scan_blocks(const int* __restrict__ deg,
                                                   int* __restrict__ incl,
                                                   int* __restrict__ bsum, int n) {
    __shared__ int s[256];
    int i = blockIdx.x * 256 + threadIdx.x;
    s[threadIdx.x] = (i < n) ? deg[i] : 0;
    __syncthreads();
#pragma unroll
    for (int off = 1; off < 256; off <<= 1) {
        int t = (threadIdx.x >= off) ? s[threadIdx.x - off] : 0;
        __syncthreads();
        s[threadIdx.x] += t;
        __syncthreads();
    }
    if (i < n) incl[i] = s[threadIdx.x];
    if (threadIdx.x == 255) bsum[blockIdx.x] = s[255];
}

__global__ __launch_bounds__(256) void scan_bsums(int* __restrict__ bsum, int nb) {
    __shared__ int s[256];
    s[threadIdx.x] = (threadIdx.x < nb) ? bsum[threadIdx.x] : 0;
    __syncthreads();
#pragma unroll
    for (int off = 1; off < 256; off <<= 1) {
        int t = (threadIdx.x >= off) ? s[threadIdx.x - off] : 0;
        __syncthreads();
        s[threadIdx.x] += t;
        __syncthreads();
    }
    if (threadIdx.x < nb) bsum[threadIdx.x] = s[threadIdx.x];
}

__global__ void finalize_rowptr(const int* __restrict__ incl, const int* __restrict__ bsum,
                                int* __restrict__ rowptr, int n) {
    int i = blockIdx.x * blockDim.x + threadIdx.x;
    if (i == 0) rowptr[0] = 0;
    if (i < n) {
        int b = i >> 8;
        int off = b ? bsum[b - 1] : 0;
        rowptr[i + 1] = incl[i] + off;
    }
}

__global__ void copy_int(const int* __restrict__ a, int* __restrict__ b, int n) {
    int i = blockIdx.x * blockDim.x + threadIdx.x;
    if (i < n) b[i] = a[i];
}
__global__ void fill_csr(const int* __restrict__ src, const int* __restrict__ dst,
                         int* __restrict__ cursor, int* __restrict__ colsrc, int e) {
    int i = blockIdx.x * blockDim.x + threadIdx.x;
    if (i < e) {
        int d = dst[i];
        int p = atomicAdd(&cursor[d], 1);
        colsrc[p] = src[i];
    }
}
__global__ void make_inv(const int* __restrict__ deg, double* __restrict__ inv, int n) {
    int i = blockIdx.x * blockDim.x + threadIdx.x;
    if (i < n) inv[i] = 1.0 / sqrt((double)(deg[i] + 1));  // +1 self loop
}

// ---------------- f32 GEMM: block = 64 rows x 128 cols ----------------
// out[M x 256] = A[gidx[M] x K] @ W[K x 256] (+bias). Per-output k-accumulation order fixed.
__global__ __launch_bounds__(256) void gemm_f32(
    const float* __restrict__ A, const int* __restrict__ gidx,
    const float* __restrict__ W, const float* __restrict__ bias,
    float* __restrict__ out, int M, int K)
{
    __shared__ float As[16][68];    // [k][row]
    __shared__ float Bs[16][132];   // [k][col 0..127]; stride%32=4 breaks bank powers
    const int tid = threadIdx.x;
    const int tx = tid & 15, ty = tid >> 4;
    const int row0 = blockIdx.x * 64, col0 = blockIdx.y * 128;
    const int sr = tid >> 2;            // 0..63 (row for A staging)
    const int skq = (tid & 3) * 4;      // k-quad for A staging
    const int bkk = tid >> 4;           // 0..15 (k-row for B staging)
    const int bc4 = (tid & 15) * 4;     // col-quad base for B staging
    const int arow = row0 + sr;
    const bool rowok = arow < M;
    long arr = 0;
    if (rowok) arr = (long)(gidx ? gidx[arow] : arow) * K;

    float acc[4][8] = {};  // [row i][col = q*4+j]
    for (int k0 = 0; k0 < K; k0 += 16) {
        float4 av = make_float4(0.f, 0.f, 0.f, 0.f);
        if (rowok) av = *reinterpret_cast<const float4*>(&A[arr + k0 + skq]);
        As[skq + 0][sr] = av.x;
        As[skq + 1][sr] = av.y;
        As[skq + 2][sr] = av.z;
        As[skq + 3][sr] = av.w;
#pragma unroll
        for (int q = 0; q < 2; ++q) {
            float4 bv = *reinterpret_cast<const float4*>(&W[(long)(k0 + bkk) * CH + col0 + q * 64 + bc4]);
            *reinterpret_cast<float4*>(&Bs[bkk][q * 64 + bc4]) = bv;
        }
        __syncthreads();
#pragma unroll
        for (int kk = 0; kk < 16; ++kk) {
            float4 a4 = *reinterpret_cast<const float4*>(&As[kk][ty * 4]);
            float a[4] = {a4.x, a4.y, a4.z, a4.w};
            float b[8];
#pragma unroll
            for (int q = 0; q < 2; ++q) {
                float4 b4 = *reinterpret_cast<const float4*>(&Bs[kk][q * 64 + tx * 4]);
                b[q * 4 + 0] = b4.x; b[q * 4 + 1] = b4.y;
                b[q * 4 + 2] = b4.z; b[q * 4 + 3] = b4.w;
            }
#pragma unroll
            for (int i = 0; i < 4; i++)
#pragma unroll
                for (int j = 0; j < 8; j++) acc[i][j] += a[i] * b[j];
        }
        __syncthreads();
    }
#pragma unroll
    for (int i = 0; i < 4; i++) {
        int row = row0 + ty * 4 + i;
        if (row >= M) continue;
#pragma unroll
        for (int q = 0; q < 2; ++q) {
            int col = col0 + q * 64 + tx * 4;
            float4 v = make_float4(acc[i][q * 4 + 0], acc[i][q * 4 + 1],
                                   acc[i][q * 4 + 2], acc[i][q * 4 + 3]);
            if (bias) {
                float4 bv = *reinterpret_cast<const float4*>(&bias[col]);
                v.x += bv.x; v.y += bv.y; v.z += bv.z; v.w += bv.w;
            }
            *reinterpret_cast<float4*>(&out[(long)row * CH + col]) = v;
        }
    }
}

// ---------------- E0-graph GCN aggregation via CSR (f64 acc) ----------------
__global__ __launch_bounds__(256) void agg_e0(
    const float* __restrict__ h, const int* __restrict__ rowptr,
    const int* __restrict__ colsrc, const double* __restrict__ inv,
    const float* __restrict__ bias, float* __restrict__ out, int n)
{
    __shared__ int s_src[256];
    __shared__ double s_nrm[256];
    int i = blockIdx.x, c = threadIdx.x;
    int r0 = rowptr[i], r1 = rowptr[i + 1];
    double invd = inv[i];
    double acc = (double)h[(long)i * CH + c] * (invd * invd);  // self loop
    for (int base = r0; base < r1; base += 256) {
        int m = min(256, r1 - base);
        __syncthreads();
        if (c < m) {
            int s = colsrc[base + c];
            s_src[c] = s;
            s_nrm[c] = invd * inv[s];
        }
        __syncthreads();
        for (int j = 0; j < m; ++j)
            acc += (double)h[(long)s_src[j] * CH + c] * s_nrm[j];
    }
    double v = acc + (double)bias[c];
    out[(long)i * CH + c] = (float)fmax(v, 0.0);
}

// ---------------- KNN-graph aggregation: mean over (k neighbors + self), f64 acc ----------------
__global__ void agg_knn(const float* __restrict__ h, const int* __restrict__ idx,
                        const float* __restrict__ b, float* __restrict__ out,
                        int n, int k, double s) {
    int i = blockIdx.x, c = threadIdx.x;
    double acc = (double)h[(long)i * CH + c];
    for (int j = 0; j < k; ++j) {
        int nb = idx[i * k + j];
        acc += (double)h[(long)nb * CH + c];
    }
    double v = acc * s + (double)b[c];
    out[(long)i * CH + c] = (float)fmax(v, 0.0);
}

// ---------------- grid-bucket exact KNN (FROZEN since R16 — matches golden) ----------------
__global__ void cell_count(const float* __restrict__ pos, int n, int G, int* __restrict__ cnt) {
    int i = blockIdx.x * blockDim.x + threadIdx.x;
    if (i < n) {
        float2 p = ((const float2*)pos)[i];
        int cx = min(G - 1, (int)(p.x * G));
        int cy = min(G - 1, (int)(p.y * G));
        atomicAdd(&cnt[cy * G + cx], 1);
    }
}
__global__ void cell_fill(const float* __restrict__ pos, int n, int G, int* __restrict__ cur,
                          float2* __restrict__ cpos, int* __restrict__ cidx) {
    int i = blockIdx.x * blockDim.x + threadIdx.x;
    if (i < n) {
        float2 p = ((const float2*)pos)[i];
        int cx = min(G - 1, (int)(p.x * G));
        int cy = min(G - 1, (int)(p.y * G));
        int t = atomicAdd(&cur[cy * G + cx], 1);
        cpos[t] = p;
        cidx[t] = i;
    }
}

template <int K>
__global__ void knn_grid(const float* __restrict__ pos, int n, int G,
                         const int* __restrict__ cellptr,
                         const float2* __restrict__ cpos,
                         const int* __restrict__ cidx,
                         int* __restrict__ outIdx) {
    int t0 = blockIdx.x * blockDim.x + threadIdx.x;
    if (t0 >= n) return;
    int q = cidx[t0];                       // cell-sorted query order
    const float INF = __int_as_float(0x7f800000);
    const float EPS = 1e-5f;
    float h = 1.0f / (float)G;
    float2 qp = cpos[t0];                   // == pos[q]
    float sqq = __fmaf_rn(qp.y, qp.y, __fmul_rn(qp.x, qp.x));
    int cx = min(G - 1, (int)(qp.x * G));
    int cy = min(G - 1, (int)(qp.y * G));
    float bd[K];
    int bi[K];
#pragma unroll
    for (int t = 0; t < K; ++t) { bd[t] = INF; bi[t] = 0x7fffffff; }

    auto visit = [&](int xx, int yy) {
        int ci = yy * G + xx;
        int s = cellptr[ci], e = cellptr[ci + 1];
        for (int t = s; t < e; ++t) {
            float2 pj = cpos[t];
            int j = cidx[t];
            float sqj = __fmaf_rn(pj.y, pj.y, __fmul_rn(pj.x, pj.x));
            float dot = __fmaf_rn(qp.y, pj.y, __fmul_rn(qp.x, pj.x));
            float t1  = __fadd_rn(sqq, sqj);
            float d   = __fmaf_rn(-2.0f, dot, t1);
            if (j == q) continue;
            if (d < bd[K - 1] || (d == bd[K - 1] && j < bi[K - 1])) {
                bd[K - 1] = d; bi[K - 1] = j;
#pragma unroll
                for (int t2 = K - 1; t2 > 0; --t2) {
                    bool sw = (bd[t2] < bd[t2 - 1]) ||
                              (bd[t2] == bd[t2 - 1] && bi[t2] < bi[t2 - 1]);
                    if (sw) {
                        float td = bd[t2]; bd[t2] = bd[t2 - 1]; bd[t2 - 1] = td;
                        int ti = bi[t2]; bi[t2] = bi[t2 - 1]; bi[t2 - 1] = ti;
                    }
                }
            }
        }
    };

    for (int c = 0; c < G; ++c) {
        if (c > 0 && bi[K - 1] != 0x7fffffff) {
            float lim = (float)(c - 1) * h;
            if (lim * lim > bd[K - 1] + EPS) break;
        }
        int y0 = max(0, cy - c), y1 = min(G - 1, cy + c);
        for (int yy = y0; yy <= y1; ++yy) {
            if (yy == cy - c || yy == cy + c) {
                int x0 = max(0, cx - c), x1 = min(G - 1, cx + c);
                for (int xx = x0; xx <= x1; ++xx) visit(xx, yy);
            } else {
                if (cx - c >= 0) visit(cx - c, yy);
                if (cx + c <= G - 1) visit(cx + c, yy);
            }
        }
    }
#pragma unroll
    for (int r = 0; r < K; ++r) outIdx[q * K + r] = bi[r];
}

// ---------------- gathers / scatters ----------------
__global__ void gather_pos(const float* __restrict__ pos, const int* __restrict__ perm,
                           float* __restrict__ out, int m) {
    int i = blockIdx.x * blockDim.x + threadIdx.x;
    if (i < m) {
        int p = perm[i];
        ((float2*)out)[i] = ((const float2*)pos)[p];
    }
}
// dst[perm[i]] = src[i]  (unpool scatter; dst pre-zeroed)
__global__ void scatter_rows(const float* __restrict__ srcb, const int* __restrict__ perm,
                             float* __restrict__ dst, int m) {
    int i = blockIdx.x, c = threadIdx.x;
    dst[(long)perm[i] * CH + c] = srcb[(long)i * CH + c];
}

extern "C" void kernel_launch(void* const* d_in, const int* in_sizes, int n_in,
                              void* d_out, int out_size, void* d_ws, size_t ws_size,
                              hipStream_t stream) {
    const float* x    = (const float*)d_in[0];
    const float* pos  = (const float*)d_in[1];
    const int*   ei   = (const int*)d_in[2];   // [2, E0]: src = ei[0:E0), dst = ei[E0:2E0)
    const int*   perm1 = (const int*)d_in[3];
    const int*   perm2 = (const int*)d_in[4];
    const int*   perm3 = (const int*)d_in[5];
    const float* Wd0 = (const float*)d_in[6],  *bd0 = (const float*)d_in[7];
    const float* Wd1 = (const float*)d_in[8],  *bd1 = (const float*)d_in[9];
    const float* Wd2 = (const float*)d_in[10], *bd2 = (const float*)d_in[11];
    const float* Wu0 = (const float*)d_in[12], *bu0 = (const float*)d_in[13];
    const float* Wu1 = (const float*)d_in[14], *bu1 = (const float*)d_in[15];
    const float* Wu2 = (const float*)d_in[16], *bu2 = (const float*)d_in[17];
    const float* Wlin = (const float*)d_in[18], *blin = (const float*)d_in[19];
    float* out = (float*)d_out;  // doubles as scratch B (fully rewritten every call)

    // workspace carve
    double* inv0 = (double*)d_ws;                 // N0 doubles
    float* pos1 = (float*)(inv0 + N0);            // N1*2 floats
    float* pos2 = pos1 + N1 * 2;                  // N2*2 floats
    float* A   = pos2 + N2 * 2;                   // N0*CH
    float* C_  = A + (long)N0 * CH;               // N1*CH
    float* D_  = C_ + (long)N1 * CH;              // N1*CH
    int* degI   = (int*)(D_ + (long)N1 * CH);     // N0
    int* rowptr = degI + N0;                      // N0+1
    int* cursor = rowptr + N0 + 1;                // N0
    int* colsrc = cursor + N0;                    // E0
    int* idx1   = colsrc + E0;                    // N1*6
    int* idx2   = idx1 + N1 * 6;                  // N2*7
    int* incl   = idx2 + N2 * 7;                  // N0 (scan stage buffer; reused for cell scans)
    int* bsum   = incl + N0;                      // NBLK
    int* cellcnt = bsum + NBLK;                   // 4096
    int* cellptr = cellcnt + 4096;                // 4097
    int* ccur    = cellptr + 4097;                // 4096
    int* cellidx = ccur + 4096;                   // N1
    float2* cellpos = (float2*)(((uintptr_t)(cellidx + N1) + 15) & ~(uintptr_t)15);  // N1 float2
    float* B = out;

    const int* e_src = ei;
    const int* e_dst = ei + E0;

    // ---- CSR + norms for the input graph ----
    hipMemsetAsync(degI, 0, (size_t)N0 * sizeof(int), stream);
    count_deg<<<(E0 + 255) / 256, 256, 0, stream>>>(e_dst, degI, E0);
    scan_blocks<<<NBLK, 256, 0, stream>>>(degI, incl, bsum, N0);
    scan_bsums<<<1, 256, 0, stream>>>(bsum, NBLK);
    finalize_rowptr<<<(N0 + 255) / 256, 256, 0, stream>>>(incl, bsum, rowptr, N0);
    copy_int<<<(N0 + 255) / 256, 256, 0, stream>>>(rowptr, cursor, N0);
    fill_csr<<<(E0 + 255) / 256, 256, 0, stream>>>(e_src, e_dst, cursor, colsrc, E0);
    make_inv<<<(N0 + 255) / 256, 256, 0, stream>>>(degI, inv0, N0);

    // ---- encoder level 0: conv(E0 graph) + relu ----
    gemm_f32<<<dim3((N0 + 63) / 64, 2), 256, 0, stream>>>(x, nullptr, Wd0, nullptr, A, N0, CIN);
    agg_e0<<<N0, 256, 0, stream>>>(A, rowptr, colsrc, inv0, bd0, B, N0);

    // ---- KNN level 1 (grid G=64, cell-sorted queries) ----
    gather_pos<<<(N1 + 255) / 256, 256, 0, stream>>>(pos, perm1, pos1, N1);
    {
        const int G1 = 64, NC1 = G1 * G1;  // 4096 cells, ~2.4 pts/cell
        hipMemsetAsync(cellcnt, 0, (size_t)NC1 * sizeof(int), stream);
        cell_count<<<(N1 + 255) / 256, 256, 0, stream>>>(pos1, N1, G1, cellcnt);
        scan_blocks<<<NC1 / 256, 256, 0, stream>>>(cellcnt, incl, bsum, NC1);
        scan_bsums<<<1, 256, 0, stream>>>(bsum, NC1 / 256);
        finalize_rowptr<<<(NC1 + 255) / 256, 256, 0, stream>>>(incl, bsum, cellptr, NC1);
        copy_int<<<(NC1 + 255) / 256, 256, 0, stream>>>(cellptr, ccur, NC1);
        cell_fill<<<(N1 + 255) / 256, 256, 0, stream>>>(pos1, N1, G1, ccur, cellpos, cellidx);
        knn_grid<6><<<(N1 + 255) / 256, 256, 0, stream>>>(pos1, N1, G1, cellptr, cellpos, cellidx, idx1);
    }

    // ---- encoder level 1 (pool via gather) ----
    gemm_f32<<<dim3((N1 + 63) / 64, 2), 256, 0, stream>>>(B, perm1, Wd1, nullptr, C_, N1, CH);
    agg_knn<<<N1, 256, 0, stream>>>(C_, idx1, bd1, D_, N1, 6, 1.0 / 7.0);

    // ---- KNN level 2 (grid G=32, cell-sorted queries) ----
    gather_pos<<<(N2 + 255) / 256, 256, 0, stream>>>(pos1, perm2, pos2, N2);
    {
        const int G2 = 32, NC2 = G2 * G2;  // 1024 cells, ~2.4 pts/cell
        hipMemsetAsync(cellcnt, 0, (size_t)NC2 * sizeof(int), stream);
        cell_count<<<(N2 + 255) / 256, 256, 0, stream>>>(pos2, N2, G2, cellcnt);
        scan_blocks<<<NC2 / 256, 256, 0, stream>>>(cellcnt, incl, bsum, NC2);
        scan_bsums<<<1, 256, 0, stream>>>(bsum, NC2 / 256);
        finalize_rowptr<<<(NC2 + 255) / 256, 256, 0, stream>>>(incl, bsum, cellptr, NC2);
        copy_int<<<(NC2 + 255) / 256, 256, 0, stream>>>(cellptr, ccur, NC2);
        cell_fill<<<(N2 + 255) / 256, 256, 0, stream>>>(pos2, N2, G2, ccur, cellpos, cellidx);
        knn_grid<7><<<(N2 + 255) / 256, 256, 0, stream>>>(pos2, N2, G2, cellptr, cellpos, cellidx, idx2);
    }

    // ---- encoder level 2 (pool via gather): Y2 in D_[0:N2) ----
    gemm_f32<<<dim3((N2 + 63) / 64, 2), 256, 0, stream>>>(D_, perm2, Wd2, nullptr, C_, N2, CH);
    agg_knn<<<N2, 256, 0, stream>>>(C_, idx2, bd2, D_, N2, 7, 1.0 / 8.0);

    // ---- decoder level 0 (N2 nodes, knn2 graph) ----
    // (scatter(Y2[perm3]))@Wu0 == scatter(Y2[perm3]@Wu0)  [zero rows give exactly +0.0]
    gemm_f32<<<dim3((N3 + 63) / 64, 2), 256, 0, stream>>>(D_, perm3, Wu0, nullptr, A, N3, CH);
    hipMemsetAsync(C_, 0, (size_t)N2 * CH * sizeof(float), stream);
    scatter_rows<<<N3, 256, 0, stream>>>(A, perm3, C_, N3);
    agg_knn<<<N2, 256, 0, stream>>>(C_, idx2, bu0, D_, N2, 7, 1.0 / 8.0);  // dec0 out in D_[0:N2)

    // ---- decoder level 1 (N1 nodes, knn1 graph) ----
    gemm_f32<<<dim3((N2 + 63) / 64, 2), 256, 0, stream>>>(D_, nullptr, Wu1, nullptr, A, N2, CH);
    hipMemsetAsync(C_, 0, (size_t)N1 * CH * sizeof(float), stream);
    scatter_rows<<<N2, 256, 0, stream>>>(A, perm2, C_, N2);
    agg_knn<<<N1, 256, 0, stream>>>(C_, idx1, bu1, D_, N1, 6, 1.0 / 7.0);  // dec1 out in D_ (N1)

    // ---- decoder level 2 (N0 nodes, E0 graph) ----
    gemm_f32<<<dim3((N1 + 63) / 64, 2), 256, 0, stream>>>(D_, nullptr, Wu2, nullptr, C_, N1, CH);
    hipMemsetAsync(B, 0, (size_t)N0 * CH * sizeof(float), stream);
    scatter_rows<<<N1, 256, 0, stream>>>(C_, perm1, B, N1);
    agg_e0<<<N0, 256, 0, stream>>>(B, rowptr, colsrc, inv0, bu2, A, N0);

    // ---- final linear ----
    gemm_f32<<<dim3((N0 + 63) / 64, 2), 256, 0, stream>>>(A, nullptr, Wlin, blin, out, N0, CH);
}

// Round 20
// 635.498 us; speedup vs baseline: 1.2041x; 1.0076x over previous
//
#include <hip/hip_runtime.h>
#include <hip/hip_bf16.h>
#include <stdint.h>

#define N0 40000
#define N1 10000
#define N2 2500
#define N3 625
#define E0 240000
#define CIN 64
#define CH 256
#define NBLK ((N0 + 255) / 256)   // 157 scan blocks

// ---------------- degree / CSR build ----------------
__global__ void count_deg(const int* __restrict__ dst, int* __restrict__ deg, int e) {
    int i = blockIdx.x * blockDim.x + threadIdx.x;
    if (i < e) atomicAdd(&deg[dst[i]], 1);
}

__global__ __launch_bounds__(256) void scan_blocks(const int* __restrict__ deg,
                                                   int* __restrict__ incl,
                                                   int* __restrict__ bsum, int n) {
    __shared__ int s[256];
    int i = blockIdx.x * 256 + threadIdx.x;
    s[threadIdx.x] = (i < n) ? deg[i] : 0;
    __syncthreads();
#pragma unroll
    for (int off = 1; off < 256; off <<= 1) {
        int t = (threadIdx.x >= off) ? s[threadIdx.x - off] : 0;
        __syncthreads();
        s[threadIdx.x] += t;
        __syncthreads();
    }
    if (i < n) incl[i] = s[threadIdx.x];
    if (threadIdx.x == 255) bsum[blockIdx.x] = s[255];
}

__global__ __launch_bounds__(256) void scan_bsums(int* __restrict__ bsum, int nb) {
    __shared__ int s[256];
    s[threadIdx.x] = (threadIdx.x < nb) ? bsum[threadIdx.x] : 0;
    __syncthreads();
#pragma unroll
    for (int off = 1; off < 256; off <<= 1) {
        int t = (threadIdx.x >= off) ? s[threadIdx.x - off] : 0;
        __syncthreads();
        s[threadIdx.x] += t;
        __syncthreads();
    }
    if (threadIdx.x < nb) bsum[threadIdx.x] = s[threadIdx.x];
}

// rowptr[0]=0; rowptr[i+1] = incl[i] + prefix(bsum); also writes cursor = rowptr[0..n-1]
__global__ void finalize_rowptr(const int* __restrict__ incl, const int* __restrict__ bsum,
                                int* __restrict__ rowptr, int* __restrict__ cursor, int n) {
    int i = blockIdx.x * blockDim.x + threadIdx.x;
    if (i == 0) { rowptr[0] = 0; cursor[0] = 0; }
    if (i < n) {
        int b = i >> 8;
        int off = b ? bsum[b - 1] : 0;
        int v = incl[i] + off;
        rowptr[i + 1] = v;
        if (i + 1 < n) cursor[i + 1] = v;
    }
}

__global__ void fill_csr(const int* __restrict__ src, const int* __restrict__ dst,
                         int* __restrict__ cursor, int* __restrict__ colsrc, int e) {
    int i = blockIdx.x * blockDim.x + threadIdx.x;
    if (i < e) {
        int d = dst[i];
        int p = atomicAdd(&cursor[d], 1);
        colsrc[p] = src[i];
    }
}
__global__ void make_inv(const int* __restrict__ deg, double* __restrict__ inv, int n) {
    int i = blockIdx.x * blockDim.x + threadIdx.x;
    if (i < n) inv[i] = 1.0 / sqrt((double)(deg[i] + 1));  // +1 self loop
}

// ---------------- f32 GEMM: 64x128 tile, reg-staged double-buffered LDS, 1 barrier/panel ----------------
// out[M x 256] = A[gidx[M] x K] @ W[K x 256] (+bias). Per-output k-accumulation order fixed.
__global__ __launch_bounds__(256) void gemm_f32(
    const float* __restrict__ A, const int* __restrict__ gidx,
    const float* __restrict__ W, const float* __restrict__ bias,
    float* __restrict__ out, int M, int K)
{
    __shared__ float As[2][16][68];
    __shared__ float Bs[2][16][132];
    const int tid = threadIdx.x;
    const int tx = tid & 15, ty = tid >> 4;
    const int row0 = blockIdx.x * 64, col0 = blockIdx.y * 128;
    const int sr = tid >> 2;            // 0..63 (row for A staging)
    const int skq = (tid & 3) * 4;      // k-quad for A staging
    const int bkk = tid >> 4;           // 0..15 (k-row for B staging)
    const int bc4 = (tid & 15) * 4;     // col-quad base for B staging
    const int arow = row0 + sr;
    const bool rowok = arow < M;
    long arr = 0;
    if (rowok) arr = (long)(gidx ? gidx[arow] : arow) * K;

    const int P = K >> 4;
    // prologue: load panel 0 and store into buffer 0
    float4 av = make_float4(0.f, 0.f, 0.f, 0.f);
    if (rowok) av = *reinterpret_cast<const float4*>(&A[arr + skq]);
    float4 bv0 = *reinterpret_cast<const float4*>(&W[(long)bkk * CH + col0 + bc4]);
    float4 bv1 = *reinterpret_cast<const float4*>(&W[(long)bkk * CH + col0 + 64 + bc4]);
    As[0][skq + 0][sr] = av.x;  As[0][skq + 1][sr] = av.y;
    As[0][skq + 2][sr] = av.z;  As[0][skq + 3][sr] = av.w;
    *reinterpret_cast<float4*>(&Bs[0][bkk][bc4]) = bv0;
    *reinterpret_cast<float4*>(&Bs[0][bkk][64 + bc4]) = bv1;
    __syncthreads();

    float acc[4][8] = {};
    for (int p = 0; p < P; ++p) {
        const int cur = p & 1;
        if (p + 1 < P) {
            int k0 = (p + 1) << 4;
            av = make_float4(0.f, 0.f, 0.f, 0.f);
            if (rowok) av = *reinterpret_cast<const float4*>(&A[arr + k0 + skq]);
            bv0 = *reinterpret_cast<const float4*>(&W[(long)(k0 + bkk) * CH + col0 + bc4]);
            bv1 = *reinterpret_cast<const float4*>(&W[(long)(k0 + bkk) * CH + col0 + 64 + bc4]);
        }
#pragma unroll
        for (int kk = 0; kk < 16; ++kk) {
            float4 a4 = *reinterpret_cast<const float4*>(&As[cur][kk][ty * 4]);
            float a[4] = {a4.x, a4.y, a4.z, a4.w};
            float b[8];
#pragma unroll
            for (int q = 0; q < 2; ++q) {
                float4 b4 = *reinterpret_cast<const float4*>(&Bs[cur][kk][q * 64 + tx * 4]);
                b[q * 4 + 0] = b4.x; b[q * 4 + 1] = b4.y;
                b[q * 4 + 2] = b4.z; b[q * 4 + 3] = b4.w;
            }
#pragma unroll
            for (int i = 0; i < 4; i++)
#pragma unroll
                for (int j = 0; j < 8; j++) acc[i][j] += a[i] * b[j];
        }
        if (p + 1 < P) {
            const int nxt = cur ^ 1;
            As[nxt][skq + 0][sr] = av.x;  As[nxt][skq + 1][sr] = av.y;
            As[nxt][skq + 2][sr] = av.z;  As[nxt][skq + 3][sr] = av.w;
            *reinterpret_cast<float4*>(&Bs[nxt][bkk][bc4]) = bv0;
            *reinterpret_cast<float4*>(&Bs[nxt][bkk][64 + bc4]) = bv1;
            __syncthreads();
        }
    }
#pragma unroll
    for (int i = 0; i < 4; i++) {
        int row = row0 + ty * 4 + i;
        if (row >= M) continue;
#pragma unroll
        for (int q = 0; q < 2; ++q) {
            int col = col0 + q * 64 + tx * 4;
            float4 v = make_float4(acc[i][q * 4 + 0], acc[i][q * 4 + 1],
                                   acc[i][q * 4 + 2], acc[i][q * 4 + 3]);
            if (bias) {
                float4 bv = *reinterpret_cast<const float4*>(&bias[col]);
                v.x += bv.x; v.y += bv.y; v.z += bv.z; v.w += bv.w;
            }
            *reinterpret_cast<float4*>(&out[(long)row * CH + col]) = v;
        }
    }
}

// ---------------- E0-graph GCN aggregation via CSR (f64 acc) ----------------
__global__ __launch_bounds__(256) void agg_e0(
    const float* __restrict__ h, const int* __restrict__ rowptr,
    const int* __restrict__ colsrc, const double* __restrict__ inv,
    const float* __restrict__ bias, float* __restrict__ out, int n)
{
    __shared__ int s_src[256];
    __shared__ double s_nrm[256];
    int i = blockIdx.x, c = threadIdx.x;
    int r0 = rowptr[i], r1 = rowptr[i + 1];
    double invd = inv[i];
    double acc = (double)h[(long)i * CH + c] * (invd * invd);  // self loop
    for (int base = r0; base < r1; base += 256) {
        int m = min(256, r1 - base);
        __syncthreads();
        if (c < m) {
            int s = colsrc[base + c];
            s_src[c] = s;
            s_nrm[c] = invd * inv[s];
        }
        __syncthreads();
        for (int j = 0; j < m; ++j)
            acc += (double)h[(long)s_src[j] * CH + c] * s_nrm[j];
    }
    double v = acc + (double)bias[c];
    out[(long)i * CH + c] = (float)fmax(v, 0.0);
}

// ---------------- KNN-graph aggregation: mean over (k neighbors + self), f64 acc ----------------
__global__ void agg_knn(const float* __restrict__ h, const int* __restrict__ idx,
                        const float* __restrict__ b, float* __restrict__ out,
                        int n, int k, double s) {
    int i = blockIdx.x, c = threadIdx.x;
    double acc = (double)h[(long)i * CH + c];
    for (int j = 0; j < k; ++j) {
        int nb = idx[i * k + j];
        acc += (double)h[(long)nb * CH + c];
    }
    double v = acc * s + (double)b[c];
    out[(long)i * CH + c] = (float)fmax(v, 0.0);
}

// ---------------- grid-bucket exact KNN (FROZEN since R16 — matches golden) ----------------
__global__ void cell_count(const float* __restrict__ pos, int n, int G, int* __restrict__ cnt) {
    int i = blockIdx.x * blockDim.x + threadIdx.x;
    if (i < n) {
        float2 p = ((const float2*)pos)[i];
        int cx = min(G - 1, (int)(p.x * G));
        int cy = min(G - 1, (int)(p.y * G));
        atomicAdd(&cnt[cy * G + cx], 1);
    }
}
__global__ void cell_fill(const float* __restrict__ pos, int n, int G, int* __restrict__ cur,
                          float2* __restrict__ cpos, int* __restrict__ cidx) {
    int i = blockIdx.x * blockDim.x + threadIdx.x;
    if (i < n) {
        float2 p = ((const float2*)pos)[i];
        int cx = min(G - 1, (int)(p.x * G));
        int cy = min(G - 1, (int)(p.y * G));
        int t = atomicAdd(&cur[cy * G + cx], 1);
        cpos[t] = p;
        cidx[t] = i;
    }
}

template <int K>
__global__ void knn_grid(const float* __restrict__ pos, int n, int G,
                         const int* __restrict__ cellptr,
                         const float2* __restrict__ cpos,
                         const int* __restrict__ cidx,
                         int* __restrict__ outIdx) {
    int t0 = blockIdx.x * blockDim.x + threadIdx.x;
    if (t0 >= n) return;
    int q = cidx[t0];                       // cell-sorted query order
    const float INF = __int_as_float(0x7f800000);
    const float EPS = 1e-5f;
    float h = 1.0f / (float)G;
    float2 qp = cpos[t0];                   // == pos[q]
    float sqq = __fmaf_rn(qp.y, qp.y, __fmul_rn(qp.x, qp.x));
    int cx = min(G - 1, (int)(qp.x * G));
    int cy = min(G - 1, (int)(qp.y * G));
    float bd[K];
    int bi[K];
#pragma unroll
    for (int t = 0; t < K; ++t) { bd[t] = INF; bi[t] = 0x7fffffff; }

    auto visit = [&](int xx, int yy) {
        int ci = yy * G + xx;
        int s = cellptr[ci], e = cellptr[ci + 1];
        for (int t = s; t < e; ++t) {
            float2 pj = cpos[t];
            int j = cidx[t];
            float sqj = __fmaf_rn(pj.y, pj.y, __fmul_rn(pj.x, pj.x));
            float dot = __fmaf_rn(qp.y, pj.y, __fmul_rn(qp.x, pj.x));
            float t1  = __fadd_rn(sqq, sqj);
            float d   = __fmaf_rn(-2.0f, dot, t1);
            if (j == q) continue;
            if (d < bd[K - 1] || (d == bd[K - 1] && j < bi[K - 1])) {
                bd[K - 1] = d; bi[K - 1] = j;
#pragma unroll
                for (int t2 = K - 1; t2 > 0; --t2) {
                    bool sw = (bd[t2] < bd[t2 - 1]) ||
                              (bd[t2] == bd[t2 - 1] && bi[t2] < bi[t2 - 1]);
                    if (sw) {
                        float td = bd[t2]; bd[t2] = bd[t2 - 1]; bd[t2 - 1] = td;
                        int ti = bi[t2]; bi[t2] = bi[t2 - 1]; bi[t2 - 1] = ti;
                    }
                }
            }
        }
    };

    for (int c = 0; c < G; ++c) {
        if (c > 0 && bi[K - 1] != 0x7fffffff) {
            float lim = (float)(c - 1) * h;
            if (lim * lim > bd[K - 1] + EPS) break;
        }
        int y0 = max(0, cy - c), y1 = min(G - 1, cy + c);
        for (int yy = y0; yy <= y1; ++yy) {
            if (yy == cy - c || yy == cy + c) {
                int x0 = max(0, cx - c), x1 = min(G - 1, cx + c);
                for (int xx = x0; xx <= x1; ++xx) visit(xx, yy);
            } else {
                if (cx - c >= 0) visit(cx - c, yy);
                if (cx + c <= G - 1) visit(cx + c, yy);
            }
        }
    }
#pragma unroll
    for (int r = 0; r < K; ++r) outIdx[q * K + r] = bi[r];
}

// ---------------- gathers / scatters ----------------
__global__ void gather_pos(const float* __restrict__ pos, const int* __restrict__ perm,
                           float* __restrict__ out, int m) {
    int i = blockIdx.x * blockDim.x + threadIdx.x;
    if (i < m) {
        int p = perm[i];
        ((float2*)out)[i] = ((const float2*)pos)[p];
    }
}
// dst[perm[i]] = src[i]  (unpool scatter; dst pre-zeroed)
__global__ void scatter_rows(const float* __restrict__ srcb, const int* __restrict__ perm,
                             float* __restrict__ dst, int m) {
    int i = blockIdx.x, c = threadIdx.x;
    dst[(long)perm[i] * CH + c] = srcb[(long)i * CH + c];
}

extern "C" void kernel_launch(void* const* d_in, const int* in_sizes, int n_in,
                              void* d_out, int out_size, void* d_ws, size_t ws_size,
                              hipStream_t stream) {
    const float* x    = (const float*)d_in[0];
    const float* pos  = (const float*)d_in[1];
    const int*   ei   = (const int*)d_in[2];   // [2, E0]: src = ei[0:E0), dst = ei[E0:2E0)
    const int*   perm1 = (const int*)d_in[3];
    const int*   perm2 = (const int*)d_in[4];
    const int*   perm3 = (const int*)d_in[5];
    const float* Wd0 = (const float*)d_in[6],  *bd0 = (const float*)d_in[7];
    const float* Wd1 = (const float*)d_in[8],  *bd1 = (const float*)d_in[9];
    const float* Wd2 = (const float*)d_in[10], *bd2 = (const float*)d_in[11];
    const float* Wu0 = (const float*)d_in[12], *bu0 = (const float*)d_in[13];
    const float* Wu1 = (const float*)d_in[14], *bu1 = (const float*)d_in[15];
    const float* Wu2 = (const float*)d_in[16], *bu2 = (const float*)d_in[17];
    const float* Wlin = (const float*)d_in[18], *blin = (const float*)d_in[19];
    float* out = (float*)d_out;  // doubles as scratch B (fully rewritten every call)

    // workspace carve
    double* inv0 = (double*)d_ws;                 // N0 doubles
    float* pos1 = (float*)(inv0 + N0);            // N1*2 floats
    float* pos2 = pos1 + N1 * 2;                  // N2*2 floats
    float* A   = pos2 + N2 * 2;                   // N0*CH
    float* C_  = A + (long)N0 * CH;               // N1*CH
    float* D_  = C_ + (long)N1 * CH;              // N1*CH
    int* degI   = (int*)(D_ + (long)N1 * CH);     // N0
    int* rowptr = degI + N0;                      // N0+1
    int* cursor = rowptr + N0 + 1;                // N0
    int* colsrc = cursor + N0;                    // E0
    int* idx1   = colsrc + E0;                    // N1*6
    int* idx2   = idx1 + N1 * 6;                  // N2*7
    int* incl   = idx2 + N2 * 7;                  // N0 (scan stage buffer; reused for cell scans)
    int* bsum   = incl + N0;                      // NBLK
    int* cellcnt = bsum + NBLK;                   // 4096
    int* cellptr = cellcnt + 4096;                // 4097
    int* ccur    = cellptr + 4097;                // 4096
    int* cellidx = ccur + 4096;                   // N1
    float2* cellpos = (float2*)(((uintptr_t)(cellidx + N1) + 15) & ~(uintptr_t)15);  // N1 float2
    float* B = out;

    const int* e_src = ei;
    const int* e_dst = ei + E0;

    // ---- CSR + norms for the input graph ----
    hipMemsetAsync(degI, 0, (size_t)N0 * sizeof(int), stream);
    count_deg<<<(E0 + 255) / 256, 256, 0, stream>>>(e_dst, degI, E0);
    scan_blocks<<<NBLK, 256, 0, stream>>>(degI, incl, bsum, N0);
    scan_bsums<<<1, 256, 0, stream>>>(bsum, NBLK);
    finalize_rowptr<<<(N0 + 255) / 256, 256, 0, stream>>>(incl, bsum, rowptr, cursor, N0);
    fill_csr<<<(E0 + 255) / 256, 256, 0, stream>>>(e_src, e_dst, cursor, colsrc, E0);
    make_inv<<<(N0 + 255) / 256, 256, 0, stream>>>(degI, inv0, N0);

    // ---- encoder level 0: conv(E0 graph) + relu ----
    gemm_f32<<<dim3((N0 + 63) / 64, 2), 256, 0, stream>>>(x, nullptr, Wd0, nullptr, A, N0, CIN);
    agg_e0<<<N0, 256, 0, stream>>>(A, rowptr, colsrc, inv0, bd0, B, N0);

    // ---- KNN level 1 (grid G=64, cell-sorted queries) ----
    gather_pos<<<(N1 + 255) / 256, 256, 0, stream>>>(pos, perm1, pos1, N1);
    {
        const int G1 = 64, NC1 = G1 * G1;  // 4096 cells, ~2.4 pts/cell
        hipMemsetAsync(cellcnt, 0, (size_t)NC1 * sizeof(int), stream);
        cell_count<<<(N1 + 255) / 256, 256, 0, stream>>>(pos1, N1, G1, cellcnt);
        scan_blocks<<<NC1 / 256, 256, 0, stream>>>(cellcnt, incl, bsum, NC1);
        scan_bsums<<<1, 256, 0, stream>>>(bsum, NC1 / 256);
        finalize_rowptr<<<(NC1 + 255) / 256, 256, 0, stream>>>(incl, bsum, cellptr, ccur, NC1);
        cell_fill<<<(N1 + 255) / 256, 256, 0, stream>>>(pos1, N1, G1, ccur, cellpos, cellidx);
        knn_grid<6><<<(N1 + 255) / 256, 256, 0, stream>>>(pos1, N1, G1, cellptr, cellpos, cellidx, idx1);
    }

    // ---- encoder level 1 (pool via gather) ----
    gemm_f32<<<dim3((N1 + 63) / 64, 2), 256, 0, stream>>>(B, perm1, Wd1, nullptr, C_, N1, CH);
    agg_knn<<<N1, 256, 0, stream>>>(C_, idx1, bd1, D_, N1, 6, 1.0 / 7.0);

    // ---- KNN level 2 (grid G=32, cell-sorted queries) ----
    gather_pos<<<(N2 + 255) / 256, 256, 0, stream>>>(pos1, perm2, pos2, N2);
    {
        const int G2 = 32, NC2 = G2 * G2;  // 1024 cells, ~2.4 pts/cell
        hipMemsetAsync(cellcnt, 0, (size_t)NC2 * sizeof(int), stream);
        cell_count<<<(N2 + 255) / 256, 256, 0, stream>>>(pos2, N2, G2, cellcnt);
        scan_blocks<<<NC2 / 256, 256, 0, stream>>>(cellcnt, incl, bsum, NC2);
        scan_bsums<<<1, 256, 0, stream>>>(bsum, NC2 / 256);
        finalize_rowptr<<<(NC2 + 255) / 256, 256, 0, stream>>>(incl, bsum, cellptr, ccur, NC2);
        cell_fill<<<(N2 + 255) / 256, 256, 0, stream>>>(pos2, N2, G2, ccur, cellpos, cellidx);
        knn_grid<7><<<(N2 + 255) / 256, 256, 0, stream>>>(pos2, N2, G2, cellptr, cellpos, cellidx, idx2);
    }

    // ---- encoder level 2 (pool via gather): Y2 in D_[0:N2) ----
    gemm_f32<<<dim3((N2 + 63) / 64, 2), 256, 0, stream>>>(D_, perm2, Wd2, nullptr, C_, N2, CH);
    agg_knn<<<N2, 256, 0, stream>>>(C_, idx2, bd2, D_, N2, 7, 1.0 / 8.0);

    // ---- decoder level 0 (N2 nodes, knn2 graph) ----
    // (scatter(Y2[perm3]))@Wu0 == scatter(Y2[perm3]@Wu0)  [zero rows give exactly +0.0]
    gemm_f32<<<dim3((N3 + 63) / 64, 2), 256, 0, stream>>>(D_, perm3, Wu0, nullptr, A, N3, CH);
    hipMemsetAsync(C_, 0, (size_t)N2 * CH * sizeof(float), stream);
    scatter_rows<<<N3, 256, 0, stream>>>(A, perm3, C_, N3);
    agg_knn<<<N2, 256, 0, stream>>>(C_, idx2, bu0, D_, N2, 7, 1.0 / 8.0);  // dec0 out in D_[0:N2)

    // ---- decoder level 1 (N1 nodes, knn1 graph) ----
    gemm_f32<<<dim3((N2 + 63) / 64, 2), 256, 0, stream>>>(D_, nullptr, Wu1, nullptr, A, N2, CH);
    hipMemsetAsync(C_, 0, (size_t)N1 * CH * sizeof(float), stream);
    scatter_rows<<<N2, 256, 0, stream>>>(A, perm2, C_, N2);
    agg_knn<<<N1, 256, 0, stream>>>(C_, idx1, bu1, D_, N1, 6, 1.0 / 7.0);  // dec1 out in D_ (N1)

    // ---- decoder level 2 (N0 nodes, E0 graph) ----
    gemm_f32<<<dim3((N1 + 63) / 64, 2), 256, 0, stream>>>(D_, nullptr, Wu2, nullptr, C_, N1, CH);
    hipMemsetAsync(B, 0, (size_t)N0 * CH * sizeof(float), stream);
    scatter_rows<<<N1, 256, 0, stream>>>(C_, perm1, B, N1);
    agg_e0<<<N0, 256, 0, stream>>>(B, rowptr, colsrc, inv0, bu2, A, N0);

    // ---- final linear ----
    gemm_f32<<<dim3((N0 + 63) / 64, 2), 256, 0, stream>>>(A, nullptr, Wlin, blin, out, N0, CH);
}